// Round 14
// baseline (1210.729 us; speedup 1.0000x reference)
//
#include <hip/hip_runtime.h>

// Match numpy's rounding exactly: no FMA contraction, same op order as reference.
#pragma clang fp contract(off)

#define B_    4
#define NT_   256
#define NZ_   192
#define NX_   192
#define NREC_ 128
#define DT_   0.001f
#define DH_   10.0f

#define N_CELL  (NZ_ * NX_)        // 36864
#define N_FIELD (B_ * N_CELL)      // 147456

#define K_     4                   // timesteps fused per launch
#define ROWS   3                   // rows owned per block (z)
#define NTHR   512                 // 8 waves/block; 2 blocks/CU co-resident
#define WR     17                  // window rows = ROWS + 2*(2K-1)
#define W4     28                  // window x-quads
#define WX     112                 // window x-cells
#define CELLS4 (WR * W4)           // 476 f4-cells (<= NTHR, one per thread)
#define TILES  (NZ_ / ROWS)        // 64 z-tiles
#define NBLK   (B_ * TILES * 2)    // 512 blocks (x split in halves)
#define NXCD   8

using f4 = __attribute__((ext_vector_type(4))) float;

__device__ __forceinline__ f4 LD4(const float* p) { return *reinterpret_cast<const f4*>(p); }
__device__ __forceinline__ void ST4(float* p, f4 v) { *reinterpret_cast<f4*>(p) = v; }

// ---------------- material precompute ----------------
__global__ void mat_kernel(const float* __restrict__ vp, const float* __restrict__ vs,
                           const float* __restrict__ rho,
                           float* __restrict__ lam, float* __restrict__ dtmu,
                           float* __restrict__ lam2mu, float* __restrict__ buoy) {
    int i = blockIdx.x * blockDim.x + threadIdx.x;
    if (i >= N_CELL) return;
    float vpi = vp[i], vsi = vs[i], rhoi = rho[i];
    float vs2 = vsi * vsi;
    float mui = rhoi * vs2;
    float lami = rhoi * (vpi * vpi - 2.0f * vs2);
    lam[i] = lami;
    dtmu[i] = DT_ * mui;             // reference: DT * mu * (...) == (DT*mu) * (...)
    lam2mu[i] = lami + 2.0f * mui;
    buoy[i] = DT_ / rhoi;
}

// ---------------- K_ fused timesteps; fixed thread->cell map; full-window compute ----
// Validity (trapezoid): v0 exact on all 17 rows (neighbors from global), then each
// phase shrinks the valid region by 1 row/col per interior side; after 8 phases the
// 3 owned rows / 96 owned cols remain exact. Global edges don't shrink (one-sided
// stencil predicates). Rim cells go stale but are never written out.
__global__ void __launch_bounds__(NTHR, 4)
step_kernel(const float* __restrict__ vxr, const float* __restrict__ vzr,
            const float* __restrict__ txxr, const float* __restrict__ tzzr,
            const float* __restrict__ txzr,
            float* __restrict__ vxw, float* __restrict__ vzw,
            float* __restrict__ txxw, float* __restrict__ tzzw, float* __restrict__ txzw,
            const float* __restrict__ lam, const float* __restrict__ dtmu,
            const float* __restrict__ l2m, const float* __restrict__ buoy,
            const float* __restrict__ wav, int t0,
            const int* __restrict__ src_loc, const int* __restrict__ rec_loc,
            float* __restrict__ out) {
    __shared__ float vxl[WR * WX];
    __shared__ float vzl[WR * WX];
    __shared__ float txxl[WR * WX];
    __shared__ float tzzl[WR * WX];
    __shared__ float txzl[WR * WX];

    const int tid  = threadIdx.x;
    // XCD-aware bijective swizzle (512 % 8 == 0): each XCD gets 64 consecutive wg
    // = one batch's contiguous z-range -> halo exchange stays in one L2.
    const int wg   = (blockIdx.x % NXCD) * (NBLK / NXCD) + blockIdx.x / NXCD;
    const int half = wg & 1;
    const int tile = (wg >> 1) & 63;
    const int b    = wg >> 7;
    const int z0   = tile * ROWS;
    const int xL   = half * 80;           // window [xL, xL+111]
    const int xa0  = half * 96;           // owned x start
    int zvL = z0 - 7;
    zvL = zvL < 0 ? 0 : (zvL > NZ_ - WR ? NZ_ - WR : zvL);   // window rows all in-bounds
    const int base = b * N_CELL;

    const int sz = src_loc[2 * b];
    const int sx = src_loc[2 * b + 1];

    const bool act = tid < CELLS4;
    const int rr = act ? (tid / W4) : 0;
    const int qq = act ? (tid - (tid / W4) * W4) : 0;
    const int z  = zvL + rr;
    const int x0 = xL + 4 * qq;
    const int lo = rr * WX + 4 * qq;
    const int oXp = (qq < W4 - 1) ? 4 : 0;
    const int oXm = (qq > 0) ? 4 : 0;
    const int oZp = (rr < WR - 1) ? WX : 0;
    const int oZm = (rr > 0) ? WX : 0;
    const int g   = base + z * NX_ + x0;
    const int c   = z * NX_ + x0;
    const int gXp = g + ((x0 < NX_ - 4) ? 4 : 0);
    const int gXm = g - ((x0 > 0) ? 4 : 0);
    const int gZm = g - ((z > 0) ? NX_ : 0);
    const int gZp = g + ((z < NZ_ - 1) ? NX_ : 0);
    const bool owned = act && (z >= z0) && (z < z0 + ROWS) && (x0 >= xa0) && (x0 < xa0 + 96);

    // receiver assignment (owned cells only; x-half dedupes the two halves)
    bool rec_ok = false;
    int rec_idx = 0;
    if (tid < NREC_) {
        int rz = rec_loc[2 * tid];
        int rx = rec_loc[2 * tid + 1];
        if (rz >= z0 && rz < z0 + ROWS && rx >= xa0 && rx < xa0 + 96) {
            rec_ok = true;
            rec_idx = (rz - zvL) * WX + (rx - xL);
        }
    }

    // own fields + materials -> registers (once per dispatch)
    f4 r_vx = {0,0,0,0}, r_vz = {0,0,0,0}, r_txx = {0,0,0,0}, r_tzz = {0,0,0,0}, r_txz = {0,0,0,0};
    f4 m_bu = {0,0,0,0}, m_l = {0,0,0,0}, m_lm = {0,0,0,0}, m_dtm = {0,0,0,0};
    if (act) {
        r_vx  = LD4(vxr + g);
        r_vz  = LD4(vzr + g);
        r_txx = LD4(txxr + g);
        r_tzz = LD4(tzzr + g);
        r_txz = LD4(txzr + g);
        m_bu  = LD4(buoy + c);
        m_l   = LD4(lam + c);
        m_lm  = LD4(l2m + c);
        m_dtm = LD4(dtmu + c);
    }

#pragma unroll
    for (int s = 0; s < K_; ++s) {
        const int t = t0 + s;

        // ---- velocity phase (own vel in regs; stress neighbors from global at s==0, else LDS) ----
        if (act) {
            f4 txn, tzp, tzm, tzzp;
            if (s == 0) {
                txn  = LD4(txxr + gXp);
                tzp  = LD4(txzr + gXm);
                tzm  = LD4(txzr + gZm);
                tzzp = LD4(tzzr + gZp);
            } else {
                txn  = LD4(txxl + lo + oXp);
                tzp  = LD4(txzl + lo - oXm);
                tzm  = LD4(txzl + lo - oZm);
                tzzp = LD4(tzzl + lo + oZp);
            }
#pragma unroll
            for (int e = 0; e < 4; ++e) {
                int xg = x0 + e;
                float txx_c = r_txx[e];
                float txxp1 = (e == 3) ? txn[0] : r_txx[e + 1];
                float txz_c = r_txz[e];
                float txzm1 = (e == 0) ? tzp[3] : r_txz[e - 1];
                float dxf_txx = (xg < NX_ - 1) ? (txxp1 - txx_c) / DH_ : 0.0f;
                float dzb_txz = (z >= 1)       ? (txz_c - tzm[e]) / DH_ : 0.0f;
                float dxb_txz = (xg >= 1)      ? (txz_c - txzm1) / DH_ : 0.0f;
                float dzf_tzz = (z < NZ_ - 1)  ? (tzzp[e] - r_tzz[e]) / DH_ : 0.0f;
                r_vx[e] = r_vx[e] + m_bu[e] * (dxf_txx + dzb_txz);
                r_vz[e] = r_vz[e] + m_bu[e] * (dxb_txz + dzf_tzz);
            }
            ST4(vxl + lo, r_vx);
            ST4(vzl + lo, r_vz);
            if (s == K_ - 1 && owned) {
                ST4(vxw + g, r_vx);
                ST4(vzw + g, r_vz);
            }
        }
        __syncthreads();

        // ---- receiver recording (post-velocity snapshot) ----
        // out layout: (NT, NREC, 2B) — out[t, r, b]=vx, out[t, r, B+b]=vz
        if (rec_ok) {
            size_t o = ((size_t)t * NREC_ + tid) * (2 * B_);
            out[o + b]      = vxl[rec_idx];
            out[o + B_ + b] = vzl[rec_idx];
        }

        // ---- stress phase (own stress in regs; vel neighbors from LDS) ----
        if (act) {
            f4 vxp  = LD4(vxl + lo - oXm);
            f4 vxzp = LD4(vxl + lo + oZp);
            f4 vzn  = LD4(vzl + lo + oXp);
            f4 vzm  = LD4(vzl + lo - oZm);
            float w = wav[b * NT_ + t];
#pragma unroll
            for (int e = 0; e < 4; ++e) {
                int xg = x0 + e;
                float vx_c = r_vx[e];
                float vz_c = r_vz[e];
                float vxm1 = (e == 0) ? vxp[3] : r_vx[e - 1];
                float vzp1 = (e == 3) ? vzn[0] : r_vz[e + 1];
                float dvxdx  = (xg >= 1)      ? (vx_c - vxm1) / DH_ : 0.0f;
                float dvzdz  = (z >= 1)       ? (vz_c - vzm[e]) / DH_ : 0.0f;
                float dzf_vx = (z < NZ_ - 1)  ? (vxzp[e] - vx_c) / DH_ : 0.0f;
                float dxf_vz = (xg < NX_ - 1) ? (vzp1 - vz_c) / DH_ : 0.0f;
                float a  = r_txx[e] + DT_ * (m_lm[e] * dvxdx + m_l[e] * dvzdz);
                float bb = r_tzz[e] + DT_ * (m_l[e] * dvxdx + m_lm[e] * dvzdz);
                float cc = r_txz[e] + m_dtm[e] * (dzf_vx + dxf_vz);
                // source injection wherever the recompute range covers it
                // (bit-identical across owner and halo-recomputing blocks)
                if (z == sz && xg == sx) { a = a + w; bb = bb + w; }
                r_txx[e] = a; r_tzz[e] = bb; r_txz[e] = cc;
            }
            ST4(txxl + lo, r_txx);
            ST4(tzzl + lo, r_tzz);
            ST4(txzl + lo, r_txz);
            if (s == K_ - 1 && owned) {
                ST4(txxw + g, r_txx);
                ST4(tzzw + g, r_tzz);
                ST4(txzw + g, r_txz);
            }
        }
        __syncthreads();
    }
}

extern "C" void kernel_launch(void* const* d_in, const int* in_sizes, int n_in,
                              void* d_out, int out_size, void* d_ws, size_t ws_size,
                              hipStream_t stream) {
    const float* xw      = (const float*)d_in[0];   // (B, NT, 1)
    const float* vp      = (const float*)d_in[1];   // (NZ, NX)
    const float* vs      = (const float*)d_in[2];
    const float* rho     = (const float*)d_in[3];
    const int*   src_loc = (const int*)d_in[4];     // (B, 2)
    const int*   rec_loc = (const int*)d_in[5];     // (NREC, 2)
    float*       out     = (float*)d_out;

    float* ws = (float*)d_ws;
    // double-buffered wavefields
    float* vx[2]  = { ws + 0 * N_FIELD, ws + 1 * N_FIELD };
    float* vz[2]  = { ws + 2 * N_FIELD, ws + 3 * N_FIELD };
    float* txx[2] = { ws + 4 * N_FIELD, ws + 5 * N_FIELD };
    float* tzz[2] = { ws + 6 * N_FIELD, ws + 7 * N_FIELD };
    float* txz[2] = { ws + 8 * N_FIELD, ws + 9 * N_FIELD };
    float* lam    = ws + 10 * N_FIELD;
    float* dtmu   = lam + N_CELL;
    float* l2m    = dtmu + N_CELL;
    float* buoy   = l2m + N_CELL;

    // zero all wavefield buffers
    hipMemsetAsync(d_ws, 0, (size_t)10 * N_FIELD * sizeof(float), stream);

    mat_kernel<<<(N_CELL + 255) / 256, 256, 0, stream>>>(vp, vs, rho, lam, dtmu, l2m, buoy);

    for (int L = 0; L < NT_ / K_; ++L) {
        int p = L & 1;
        step_kernel<<<NBLK, NTHR, 0, stream>>>(
            vx[p], vz[p], txx[p], tzz[p], txz[p],
            vx[1 - p], vz[1 - p], txx[1 - p], tzz[1 - p], txz[1 - p],
            lam, dtmu, l2m, buoy,
            xw, L * K_, src_loc, rec_loc, out);
    }
}